// Round 15
// baseline (528.725 us; speedup 1.0000x reference)
//
#include <hip/hip_runtime.h>

#define NTOK 343
#define NPAD 352
#define DIM 384
#define NHEAD 12
#define HDIM 32
#define NWIN 64
#define BATCH 128
#define SCALE 0.17677669529663687f
#define LOG2E 1.4426950408889634f
#define SCLG2 (0.17677669529663687f * 1.4426950408889634f)
#define NN 117649   // 343*343
#define MG 88       // NPAD/4 m-groups
#define GSTRIDE 1372  // NTOK*4 elems per m-group

// prep_kernel segment block counts (all exact, 256 threads/block)
#define GB 5660    // bias: 12*88*343*4 = 1,448,832 elems
#define GM 30184   // mask: 64*88*343*4 = 7,727,104
#define GS 8232    // skip cvt: 2,107,392 x8-groups
#define GWK 144    // w_kv cvt: 36,864 x8-groups
#define GWP 72     // w_proj cvt: 18,432 x8-groups

typedef __attribute__((ext_vector_type(8))) short bf16x8;
typedef __attribute__((ext_vector_type(4))) short bf16x4;
typedef __attribute__((ext_vector_type(4))) float f32x4;
typedef __attribute__((ext_vector_type(4))) int i32x4;
typedef __attribute__((ext_vector_type(2))) int i32x2;

static __device__ inline short f2bf(float f) {
  union { float f; unsigned u; } v; v.f = f;
  unsigned r = v.u + 0x7fffu + ((v.u >> 16) & 1u);
  return (short)(r >> 16);
}
static __device__ inline float asfu(unsigned u) {
  union { unsigned u; float f; } v; v.u = u; return v.f;
}
// fast pack: +0x8000 round-to-nearest, v_perm grabs the two high halves (3 VALU).
static __device__ inline int pack2rn(float lo, float hi) {
  union { float f; unsigned u; } a, b;
  a.f = lo; b.f = hi;
  unsigned au = a.u + 0x8000u;
  unsigned bu = b.u + 0x8000u;
  return (int)__builtin_amdgcn_perm(bu, au, 0x07060302u);
}
static __device__ inline short f2bfrn(float f) {
  union { float f; unsigned u; } v; v.f = f;
  return (short)((v.u + 0x8000u) >> 16);
}
static __device__ inline float fexp2(float x) {
  return __builtin_amdgcn_exp2f(x);
}

#define MFMA16(a, b, c) __builtin_amdgcn_mfma_f32_16x16x32_bf16((a), (b), (c), 0, 0, 0)

// ---------- kernel 0: merged prep (bias, mask, skip->bf16, W->bf16) ---------
static __device__ inline void cvt8(const float* __restrict__ in,
                                   short* __restrict__ out, int i, int n8) {
  if (i >= n8) return;
  f32x4 a = *(const f32x4*)(in + (size_t)i * 8);
  f32x4 b = *(const f32x4*)(in + (size_t)i * 8 + 4);
  bf16x8 o;
#pragma unroll
  for (int j = 0; j < 4; ++j) {
    o[j] = f2bf(a[j]);
    o[j + 4] = f2bf(b[j]);
  }
  *(bf16x8*)(out + (size_t)i * 8) = o;
}

__global__ __launch_bounds__(256) void prep_kernel(
    const float* __restrict__ table, const int* __restrict__ rpi,
    short* __restrict__ bias_b4, const float* __restrict__ mask,
    short* __restrict__ mask_b4, const float* __restrict__ skip,
    short* __restrict__ skip_bf, const float* __restrict__ wkv,
    short* __restrict__ wkv_bf, const float* __restrict__ wproj,
    short* __restrict__ wproj_bf) {
  const int g = blockIdx.x;
  const int tid = threadIdx.x;
  if (g < GB) {
    int idx = g * 256 + tid;
    if (idx >= NHEAD * MG * NTOK * 4) return;
    int r = idx & 3;
    int t = idx >> 2;
    int q = t % NTOK;
    int u = t / NTOK;
    int gg = u % MG;
    int h = u / MG;
    int m = gg * 4 + r;
    bias_b4[idx] = (m < NTOK) ? f2bf(table[rpi[q * NTOK + m] * NHEAD + h] * LOG2E)
                              : f2bf(-1e30f);
  } else if (g < GB + GM) {
    int idx = (g - GB) * 256 + tid;
    int r = idx & 3;
    int t = idx >> 2;
    int q = t % NTOK;
    int u = t / NTOK;
    int gg = u % MG;
    int w = u / MG;
    int m = gg * 4 + r;
    mask_b4[idx] = (m < NTOK) ? f2bf(mask[(size_t)w * NN + q * NTOK + m] * LOG2E) : 0;
  } else if (g < GB + GM + GS) {
    cvt8(skip, skip_bf, (g - GB - GM) * 256 + tid, BATCH * NTOK * DIM / 8);
  } else if (g < GB + GM + GS + GWK) {
    cvt8(wkv, wkv_bf, (g - GB - GM - GS) * 256 + tid, 2 * DIM * DIM / 8);
  } else {
    cvt8(wproj, wproj_bf, (g - GB - GM - GS - GWK) * 256 + tid, DIM * DIM / 8);
  }
}

// ---------- kernel 1: kv = skip_bf @ wkv_bf^T + b_kv -> K_ws/V_ws (bf16) ----
__global__ __launch_bounds__(256) void kv_proj_kernel(
    const short* __restrict__ Xbf, const short* __restrict__ Wbf,
    const float* __restrict__ bkv, short* __restrict__ Kws,
    short* __restrict__ Vws) {
  __shared__ short As[128][40];
  __shared__ short Bs[128][40];
  const int L = blockIdx.x;            // 0..2057; XCD = L & 7
  const int xcd = L & 7;
  const int j8 = L >> 3;
  const int wg = ((xcd < 2) ? xcd * 258 : 516 + (xcd - 2) * 257) + j8;
  const int n0 = (wg % 6) * 128;
  const int m0 = (wg / 6) * 128;
  const int tid = threadIdx.x;
  const int lane = tid & 63;
  const int wave = tid >> 6;
  const int wm = (wave >> 1) * 64;
  const int wn = (wave & 1) * 64;
  const int lr = lane & 15;
  const int lk = (lane >> 4) * 8;
  const int arow = tid >> 2;        // 0..63
  const int acol8 = (tid & 3) * 8;  // 0,8,16,24
  const f32x4 zero4 = {0.f, 0.f, 0.f, 0.f};

  f32x4 acc[4][4];
#pragma unroll
  for (int m = 0; m < 4; ++m)
#pragma unroll
    for (int n = 0; n < 4; ++n) acc[m][n] = zero4;

  for (int kk = 0; kk < 12; ++kk) {
    __syncthreads();
    *(bf16x8*)(&As[arow][acol8]) =
        *(const bf16x8*)(Xbf + (size_t)(m0 + arow) * DIM + kk * 32 + acol8);
    *(bf16x8*)(&As[arow + 64][acol8]) =
        *(const bf16x8*)(Xbf + (size_t)(m0 + arow + 64) * DIM + kk * 32 + acol8);
    *(bf16x8*)(&Bs[arow][acol8]) =
        *(const bf16x8*)(Wbf + (size_t)(n0 + arow) * DIM + kk * 32 + acol8);
    *(bf16x8*)(&Bs[arow + 64][acol8]) =
        *(const bf16x8*)(Wbf + (size_t)(n0 + arow + 64) * DIM + kk * 32 + acol8);
    __syncthreads();
    bf16x8 af[4], bf[4];
#pragma unroll
    for (int m = 0; m < 4; ++m) af[m] = *(const bf16x8*)(&As[wm + m * 16 + lr][lk]);
#pragma unroll
    for (int n = 0; n < 4; ++n) bf[n] = *(const bf16x8*)(&Bs[wn + n * 16 + lr][lk]);
#pragma unroll
    for (int m = 0; m < 4; ++m)
#pragma unroll
      for (int n = 0; n < 4; ++n) acc[m][n] = MFMA16(af[m], bf[n], acc[m][n]);
  }

  const int rq = (lane >> 4) * 4;
#pragma unroll
  for (int n = 0; n < 4; ++n) {
    int gcol = n0 + wn + n * 16 + lr;
    float bias = bkv[gcol];
    int c = (gcol >= DIM) ? (gcol - DIM) : gcol;  // gcol % 384
    int h = c >> 5;
    int hd = c & 31;
    short* dst = (gcol < DIM) ? Kws : Vws;
#pragma unroll
    for (int m = 0; m < 4; ++m) {
#pragma unroll
      for (int r = 0; r < 4; ++r) {
        int grow = m0 + wm + m * 16 + rq + r;
        int bb = grow / NTOK;
        int tok = grow - bb * NTOK;
        dst[(((size_t)bb * NHEAD + h) * NTOK + tok) * HDIM + hd] =
            f2bf(acc[m][n][r] + bias);
      }
    }
  }
}

// ---------- kernel 2: fused attention per (b, h) — swapped-QK^T form --------
// R15: cross-qt register prefetch of bias/mask (T14). Raw bf16 bits live in
// Rb/Rm[22]; qt+1's 44 loads are issued right after qt's P-pack (s[] dead),
// hidden under PV MFMAs + epilogue + next Q-load. Unpack (<<16 / &0xFFFF0000
// + fadd) is bit-exact with the previous bf2f adds.
__global__ __launch_bounds__(256, 3) void attn_kernel(
    const float* __restrict__ x_up, const short* __restrict__ mask_b4,
    const short* __restrict__ bias_b4, const short* __restrict__ Kws,
    const short* __restrict__ Vws, const float* __restrict__ pos,
    short* __restrict__ attn_out) {
  __shared__ short Ksm[NPAD][40];      // K[key][ch], col ^= (key&8)
  __shared__ short Vp[HDIM][NPAD + 8]; // V^T[ch][pi(key) ^ (ch&8)]
  const int bid = blockIdx.x;
  const int xcd = bid & 7;
  const int jj = bid >> 3;                 // 0..191
  const int win = xcd * 8 + jj / 24;       // 0..63, pinned to xcd
  const int rep = jj - (jj / 24) * 24;     // 0..23
  const int h = rep % NHEAD;
  const int b = win + ((rep >= NHEAD) ? 64 : 0);
  const int tid = threadIdx.x;
  const int wave = tid >> 6;
  const int lane = tid & 63;
  const int lr = lane & 15;
  const int lg = lane >> 4;
  const int koff = lg * 8;
  const int koff_s = koff ^ (lane & 8);
  const f32x4 zero4 = {0.f, 0.f, 0.f, 0.f};

  const short* Kb = Kws + ((size_t)b * NHEAD + h) * NTOK * HDIM;
  const short* Vb = Vws + ((size_t)b * NHEAD + h) * NTOK * HDIM;
  {
    const int c8 = (tid & 3) * 8;
    const int rb = tid >> 2;
    const bf16x8 z8 = {0, 0, 0, 0, 0, 0, 0, 0};
#pragma unroll
    for (int r0 = 0; r0 < 384; r0 += 64) {
      int row = r0 + rb;
      if (row < NPAD) {
        bf16x8 kv = z8;
        if (row < NTOK) kv = *(const bf16x8*)(Kb + row * HDIM + c8);
        *(bf16x8*)(&Ksm[row][c8 ^ (row & 8)]) = kv;
      }
    }
#pragma unroll
    for (int r0 = 0; r0 < 384; r0 += 64) {
      int row = r0 + rb;
      if (row < NPAD) {
        bf16x8 vv = z8;
        if (row < NTOK) vv = *(const bf16x8*)(Vb + row * HDIM + c8);
        // pi(row): k-slot = ((m&16)>>2) | ((m&12)<<1) | (m&3) within 32-block
        int p = (row & ~31) | ((row & 12) << 1) | ((row & 16) >> 2) | (row & 3);
#pragma unroll
        for (int i = 0; i < 8; ++i)
          Vp[c8 + i][p ^ ((c8 + i) & 8)] = vv[i];
      }
    }
  }
  __syncthreads();

  const size_t bbase = (size_t)h * MG * GSTRIDE + (size_t)lg * GSTRIDE;
  const size_t mbase = (size_t)win * MG * GSTRIDE + (size_t)lg * GSTRIDE;
  i32x2 Rb[22], Rm[22];
  {
    // prologue: prefetch qt=0 (q0 = wave*16, always < NTOK)
    int qi = wave * 16 + lr;
    const short* bq = bias_b4 + bbase + (size_t)qi * 4;
    const short* mq = mask_b4 + mbase + (size_t)qi * 4;
#pragma unroll
    for (int j = 0; j < 22; ++j) {
      Rb[j] = *(const i32x2*)(bq + (size_t)j * 4 * GSTRIDE);
      Rm[j] = *(const i32x2*)(mq + (size_t)j * 4 * GSTRIDE);
    }
  }

  for (int qt = 0; qt < 6; ++qt) {
    const int q0 = qt * 64 + wave * 16;
    if (q0 >= NTOK) continue;  // only qt5, waves 2-3
    const int qn = q0 + lr;
    const int qidx = (qn < NTOK) ? qn : (NTOK - 1);
    // Q B-frag scaled by SCALE*LOG2E (exp2 domain)
    bf16x8 qf;
    {
      const float* qp = x_up + ((size_t)b * NTOK + qidx) * DIM + h * HDIM + koff;
      f32x4 v0 = *(const f32x4*)qp;
      f32x4 v1 = *(const f32x4*)(qp + 4);
#pragma unroll
      for (int i = 0; i < 4; ++i) {
        qf[i] = f2bfrn(v0[i] * SCLG2);
        qf[i + 4] = f2bfrn(v1[i] * SCLG2);
      }
    }
    // unpack prefetched bias+mask -> C-in (bit-exact with bf2f adds)
    f32x4 s[22];
#pragma unroll
    for (int j = 0; j < 22; ++j) {
      unsigned b0 = (unsigned)Rb[j][0], b1 = (unsigned)Rb[j][1];
      unsigned c0 = (unsigned)Rm[j][0], c1 = (unsigned)Rm[j][1];
      s[j][0] = asfu(b0 << 16) + asfu(c0 << 16);
      s[j][1] = asfu(b0 & 0xFFFF0000u) + asfu(c0 & 0xFFFF0000u);
      s[j][2] = asfu(b1 << 16) + asfu(c1 << 16);
      s[j][3] = asfu(b1 & 0xFFFF0000u) + asfu(c1 & 0xFFFF0000u);
    }
    // S^T tiles: s[j] = K_j * Q + (bias+mask)
    __builtin_amdgcn_s_setprio(1);
#pragma unroll
    for (int j = 0; j < 22; ++j) {
      bf16x8 kf = *(const bf16x8*)(&Ksm[j * 16 + lr][koff_s]);
      s[j] = MFMA16(kf, qf, s[j]);
    }
    __builtin_amdgcn_s_setprio(0);
    // p = exp2(s) (no max-sub; bounded). P packed UNNORMALIZED.
    f32x4 sum4 = zero4;
    i32x4 up4[11];
#pragma unroll
    for (int j = 0; j < 22; ++j) {
      f32x4 p;
#pragma unroll
      for (int r = 0; r < 4; ++r) p[r] = fexp2(s[j][r]);
      sum4 += p;
      up4[j >> 1][(j & 1) * 2 + 0] = pack2rn(p[0], p[1]);
      up4[j >> 1][(j & 1) * 2 + 1] = pack2rn(p[2], p[3]);
    }
    // prefetch qt+1's bias/mask NOW (s dead) — lands during PV + epilogue
    if (qt < 5) {
      const int q0n = q0 + 64;
      if (q0n < NTOK) {
        int qin = q0n + lr;
        if (qin >= NTOK) qin = NTOK - 1;
        const short* bq = bias_b4 + bbase + (size_t)qin * 4;
        const short* mq = mask_b4 + mbase + (size_t)qin * 4;
#pragma unroll
        for (int j = 0; j < 22; ++j) {
          Rb[j] = *(const i32x2*)(bq + (size_t)j * 4 * GSTRIDE);
          Rm[j] = *(const i32x2*)(mq + (size_t)j * 4 * GSTRIDE);
        }
      }
    }
    float sum = (sum4[0] + sum4[1]) + (sum4[2] + sum4[3]);
    sum += __shfl_xor(sum, 16);
    sum += __shfl_xor(sum, 32);
    const float inv = 1.0f / sum;

    // O^T = V^T_pi * P~ (unnormalized)
    f32x4 o0 = zero4;
    f32x4 o1 = zero4;
    __builtin_amdgcn_s_setprio(1);
#pragma unroll
    for (int kt = 0; kt < 11; ++kt) {
      bf16x8 pf = __builtin_bit_cast(bf16x8, up4[kt]);
      bf16x8 a0 = *(const bf16x8*)(&Vp[lr][kt * 32 + koff_s]);
      bf16x8 a1 = *(const bf16x8*)(&Vp[16 + lr][kt * 32 + koff_s]);
      o0 = MFMA16(a0, pf, o0);
      o1 = MFMA16(a1, pf, o1);
    }
    __builtin_amdgcn_s_setprio(0);
    // O is UNNORMALIZED -> the *inv below is REQUIRED, exactly once.
    if (qn < NTOK) {
      const float* pp = pos + ((size_t)b * NTOK + qn) * DIM + h * HDIM + 4 * lg;
      f32x4 p0 = *(const f32x4*)pp;
      f32x4 p1 = *(const f32x4*)(pp + 16);
      short* op = attn_out + ((size_t)b * NTOK + qn) * DIM + h * HDIM + 4 * lg;
      *(int*)(op + 0) = pack2rn(o0[0] * inv + p0[0], o0[1] * inv + p0[1]);
      *(int*)(op + 2) = pack2rn(o0[2] * inv + p0[2], o0[3] * inv + p0[3]);
      *(int*)(op + 16) = pack2rn(o1[0] * inv + p1[0], o1[1] * inv + p1[1]);
      *(int*)(op + 18) = pack2rn(o1[2] * inv + p1[2], o1[3] * inv + p1[3]);
    }
  }
}

// ---------- kernel 3: out = Xa @ wproj_bf^T + b_proj (Xa = attn+pos) --------
__global__ __launch_bounds__(256) void out_proj_kernel(
    const short* __restrict__ Xa, const short* __restrict__ Wbf,
    const float* __restrict__ bpr, float* __restrict__ out) {
  __shared__ short As[128][40];
  __shared__ short Bs[128][40];
  const int L = blockIdx.x;            // 0..1028
  const int xcd = L & 7;
  const int j8 = L >> 3;
  const int wg = ((xcd < 5) ? xcd * 129 : 645 + (xcd - 5) * 128) + j8;
  const int n0 = (wg % 3) * 128;
  const int m0 = (wg / 3) * 128;
  const int tid = threadIdx.x;
  const int lane = tid & 63;
  const int wave = tid >> 6;
  const int wm = (wave >> 1) * 64;
  const int wn = (wave & 1) * 64;
  const int lr = lane & 15;
  const int lk = (lane >> 4) * 8;
  const int arow = tid >> 2;
  const int acol8 = (tid & 3) * 8;
  const f32x4 zero4 = {0.f, 0.f, 0.f, 0.f};

  f32x4 acc[4][4];
#pragma unroll
  for (int m = 0; m < 4; ++m)
#pragma unroll
    for (int n = 0; n < 4; ++n) acc[m][n] = zero4;

  for (int kk = 0; kk < 12; ++kk) {
    __syncthreads();
    *(bf16x8*)(&As[arow][acol8]) =
        *(const bf16x8*)(Xa + (size_t)(m0 + arow) * DIM + kk * 32 + acol8);
    *(bf16x8*)(&As[arow + 64][acol8]) =
        *(const bf16x8*)(Xa + (size_t)(m0 + arow + 64) * DIM + kk * 32 + acol8);
    *(bf16x8*)(&Bs[arow][acol8]) =
        *(const bf16x8*)(Wbf + (size_t)(n0 + arow) * DIM + kk * 32 + acol8);
    *(bf16x8*)(&Bs[arow + 64][acol8]) =
        *(const bf16x8*)(Wbf + (size_t)(n0 + arow + 64) * DIM + kk * 32 + acol8);
    __syncthreads();
    bf16x8 af[4], bf[4];
#pragma unroll
    for (int m = 0; m < 4; ++m) af[m] = *(const bf16x8*)(&As[wm + m * 16 + lr][lk]);
#pragma unroll
    for (int n = 0; n < 4; ++n) bf[n] = *(const bf16x8*)(&Bs[wn + n * 16 + lr][lk]);
#pragma unroll
    for (int m = 0; m < 4; ++m)
#pragma unroll
      for (int n = 0; n < 4; ++n) acc[m][n] = MFMA16(af[m], bf[n], acc[m][n]);
  }

  const int rq = (lane >> 4) * 4;
#pragma unroll
  for (int n = 0; n < 4; ++n) {
    int gcol = n0 + wn + n * 16 + lr;
    float bias = bpr[gcol];
#pragma unroll
    for (int m = 0; m < 4; ++m) {
#pragma unroll
      for (int r = 0; r < 4; ++r) {
        int grow = m0 + wm + m * 16 + rq + r;
        out[(size_t)grow * DIM + gcol] = acc[m][n][r] + bias;
      }
    }
  }
}

extern "C" void kernel_launch(void* const* d_in, const int* in_sizes, int n_in,
                              void* d_out, int out_size, void* d_ws, size_t ws_size,
                              hipStream_t stream) {
  const float* skip = (const float*)d_in[0];
  const float* x_up = (const float*)d_in[1];
  const float* pos = (const float*)d_in[2];
  const float* mask = (const float*)d_in[3];
  const float* w_kv = (const float*)d_in[4];
  const float* b_kv = (const float*)d_in[5];
  const float* w_proj = (const float*)d_in[6];
  const float* b_proj = (const float*)d_in[7];
  const float* bias_table = (const float*)d_in[8];
  const int* rpi = (const int*)d_in[9];
  float* out = (float*)d_out;

  char* ws = (char*)d_ws;
  const size_t kv_bytes = (size_t)BATCH * NHEAD * NTOK * HDIM * 2;   // 33,718,272
  const size_t bias_bytes = (size_t)NHEAD * MG * NTOK * 4 * 2;       //  2,897,664
  const size_t mask_bytes = (size_t)NWIN * MG * NTOK * 4 * 2;        // 15,454,208
  const size_t wkv_bytes = (size_t)2 * DIM * DIM * 2;                //    589,824
  const size_t wpr_bytes = (size_t)DIM * DIM * 2;                    //    294,912
  short* Kws = (short*)ws;
  short* Vws = (short*)(ws + kv_bytes);
  short* bias_b4 = (short*)(ws + 2 * kv_bytes);
  short* mask_b4 = (short*)(ws + 2 * kv_bytes + bias_bytes);
  short* wkv_bf = (short*)(ws + 2 * kv_bytes + bias_bytes + mask_bytes);
  short* wproj_bf = (short*)(ws + 2 * kv_bytes + bias_bytes + mask_bytes + wkv_bytes);
  // skip_bf and attn_ws alias: prep->kv_proj finish before attn writes it
  short* skip_bf = (short*)(ws + 2 * kv_bytes + bias_bytes + mask_bytes +
                            wkv_bytes + wpr_bytes);
  short* attn_ws = skip_bf;

  prep_kernel<<<dim3(GB + GM + GS + GWK + GWP), dim3(256), 0, stream>>>(
      bias_table, rpi, bias_b4, mask, mask_b4, skip, skip_bf, w_kv, wkv_bf,
      w_proj, wproj_bf);
  kv_proj_kernel<<<dim3(2058), dim3(256), 0, stream>>>(skip_bf, wkv_bf, b_kv,
                                                       Kws, Vws);
  attn_kernel<<<dim3(BATCH * NHEAD), dim3(256), 0, stream>>>(
      x_up, mask_b4, bias_b4, Kws, Vws, pos, attn_ws);
  out_proj_kernel<<<dim3(1029), dim3(256), 0, stream>>>(attn_ws, wproj_bf,
                                                        b_proj, out);
}

// Round 16
// 259.120 us; speedup vs baseline: 2.0405x; 2.0405x over previous
//
#include <hip/hip_runtime.h>

#define NTOK 343
#define NPAD 352
#define DIM 384
#define NHEAD 12
#define HDIM 32
#define NWIN 64
#define BATCH 128
#define SCALE 0.17677669529663687f
#define LOG2E 1.4426950408889634f
#define SCLG2 (0.17677669529663687f * 1.4426950408889634f)
#define NN 117649   // 343*343
#define MG 88       // NPAD/4 m-groups
#define GSTRIDE 1372  // NTOK*4 elems per m-group

// prep_kernel segment block counts (all exact, 256 threads/block)
#define GB 5660    // bias: 12*88*343*4 = 1,448,832 elems
#define GM 30184   // mask: 64*88*343*4 = 7,727,104
#define GS 8232    // skip cvt: 2,107,392 x8-groups
#define GWK 144    // w_kv cvt: 36,864 x8-groups
#define GWP 72     // w_proj cvt: 18,432 x8-groups

typedef __attribute__((ext_vector_type(8))) short bf16x8;
typedef __attribute__((ext_vector_type(4))) short bf16x4;
typedef __attribute__((ext_vector_type(4))) float f32x4;
typedef __attribute__((ext_vector_type(4))) int i32x4;

static __device__ inline short f2bf(float f) {
  union { float f; unsigned u; } v; v.f = f;
  unsigned r = v.u + 0x7fffu + ((v.u >> 16) & 1u);
  return (short)(r >> 16);
}
static __device__ inline float bf2f(short s) {
  union { unsigned u; float f; } v; v.u = ((unsigned)(unsigned short)s) << 16;
  return v.f;
}
// fast pack: +0x8000 round-to-nearest, v_perm grabs the two high halves (3 VALU).
static __device__ inline int pack2rn(float lo, float hi) {
  union { float f; unsigned u; } a, b;
  a.f = lo; b.f = hi;
  unsigned au = a.u + 0x8000u;
  unsigned bu = b.u + 0x8000u;
  return (int)__builtin_amdgcn_perm(bu, au, 0x07060302u);
}
static __device__ inline short f2bfrn(float f) {
  union { float f; unsigned u; } v; v.f = f;
  return (short)((v.u + 0x8000u) >> 16);
}
static __device__ inline float fexp2(float x) {
  return __builtin_amdgcn_exp2f(x);
}

#define MFMA16(a, b, c) __builtin_amdgcn_mfma_f32_16x16x32_bf16((a), (b), (c), 0, 0, 0)

// ---------- kernel 0: merged prep (bias, mask, skip->bf16, W->bf16) ---------
static __device__ inline void cvt8(const float* __restrict__ in,
                                   short* __restrict__ out, int i, int n8) {
  if (i >= n8) return;
  f32x4 a = *(const f32x4*)(in + (size_t)i * 8);
  f32x4 b = *(const f32x4*)(in + (size_t)i * 8 + 4);
  bf16x8 o;
#pragma unroll
  for (int j = 0; j < 4; ++j) {
    o[j] = f2bf(a[j]);
    o[j + 4] = f2bf(b[j]);
  }
  *(bf16x8*)(out + (size_t)i * 8) = o;
}

__global__ __launch_bounds__(256) void prep_kernel(
    const float* __restrict__ table, const int* __restrict__ rpi,
    short* __restrict__ bias_b4, const float* __restrict__ mask,
    short* __restrict__ mask_b4, const float* __restrict__ skip,
    short* __restrict__ skip_bf, const float* __restrict__ wkv,
    short* __restrict__ wkv_bf, const float* __restrict__ wproj,
    short* __restrict__ wproj_bf) {
  const int g = blockIdx.x;
  const int tid = threadIdx.x;
  if (g < GB) {
    int idx = g * 256 + tid;
    if (idx >= NHEAD * MG * NTOK * 4) return;
    int r = idx & 3;
    int t = idx >> 2;
    int q = t % NTOK;
    int u = t / NTOK;
    int gg = u % MG;
    int h = u / MG;
    int m = gg * 4 + r;
    bias_b4[idx] = (m < NTOK) ? f2bf(table[rpi[q * NTOK + m] * NHEAD + h] * LOG2E)
                              : f2bf(-1e30f);
  } else if (g < GB + GM) {
    int idx = (g - GB) * 256 + tid;
    int r = idx & 3;
    int t = idx >> 2;
    int q = t % NTOK;
    int u = t / NTOK;
    int gg = u % MG;
    int w = u / MG;
    int m = gg * 4 + r;
    mask_b4[idx] = (m < NTOK) ? f2bf(mask[(size_t)w * NN + q * NTOK + m] * LOG2E) : 0;
  } else if (g < GB + GM + GS) {
    cvt8(skip, skip_bf, (g - GB - GM) * 256 + tid, BATCH * NTOK * DIM / 8);
  } else if (g < GB + GM + GS + GWK) {
    cvt8(wkv, wkv_bf, (g - GB - GM - GS) * 256 + tid, 2 * DIM * DIM / 8);
  } else {
    cvt8(wproj, wproj_bf, (g - GB - GM - GS - GWK) * 256 + tid, DIM * DIM / 8);
  }
}

// ---------- kernel 1: kv = skip_bf @ wkv_bf^T + b_kv -> K_ws/V_ws (bf16) ----
__global__ __launch_bounds__(256) void kv_proj_kernel(
    const short* __restrict__ Xbf, const short* __restrict__ Wbf,
    const float* __restrict__ bkv, short* __restrict__ Kws,
    short* __restrict__ Vws) {
  __shared__ short As[128][40];
  __shared__ short Bs[128][40];
  const int L = blockIdx.x;            // 0..2057; XCD = L & 7
  const int xcd = L & 7;
  const int j8 = L >> 3;
  const int wg = ((xcd < 2) ? xcd * 258 : 516 + (xcd - 2) * 257) + j8;
  const int n0 = (wg % 6) * 128;
  const int m0 = (wg / 6) * 128;
  const int tid = threadIdx.x;
  const int lane = tid & 63;
  const int wave = tid >> 6;
  const int wm = (wave >> 1) * 64;
  const int wn = (wave & 1) * 64;
  const int lr = lane & 15;
  const int lk = (lane >> 4) * 8;
  const int arow = tid >> 2;        // 0..63
  const int acol8 = (tid & 3) * 8;  // 0,8,16,24
  const f32x4 zero4 = {0.f, 0.f, 0.f, 0.f};

  f32x4 acc[4][4];
#pragma unroll
  for (int m = 0; m < 4; ++m)
#pragma unroll
    for (int n = 0; n < 4; ++n) acc[m][n] = zero4;

  for (int kk = 0; kk < 12; ++kk) {
    __syncthreads();
    *(bf16x8*)(&As[arow][acol8]) =
        *(const bf16x8*)(Xbf + (size_t)(m0 + arow) * DIM + kk * 32 + acol8);
    *(bf16x8*)(&As[arow + 64][acol8]) =
        *(const bf16x8*)(Xbf + (size_t)(m0 + arow + 64) * DIM + kk * 32 + acol8);
    *(bf16x8*)(&Bs[arow][acol8]) =
        *(const bf16x8*)(Wbf + (size_t)(n0 + arow) * DIM + kk * 32 + acol8);
    *(bf16x8*)(&Bs[arow + 64][acol8]) =
        *(const bf16x8*)(Wbf + (size_t)(n0 + arow + 64) * DIM + kk * 32 + acol8);
    __syncthreads();
    bf16x8 af[4], bf[4];
#pragma unroll
    for (int m = 0; m < 4; ++m) af[m] = *(const bf16x8*)(&As[wm + m * 16 + lr][lk]);
#pragma unroll
    for (int n = 0; n < 4; ++n) bf[n] = *(const bf16x8*)(&Bs[wn + n * 16 + lr][lk]);
#pragma unroll
    for (int m = 0; m < 4; ++m)
#pragma unroll
      for (int n = 0; n < 4; ++n) acc[m][n] = MFMA16(af[m], bf[n], acc[m][n]);
  }

  const int rq = (lane >> 4) * 4;
#pragma unroll
  for (int n = 0; n < 4; ++n) {
    int gcol = n0 + wn + n * 16 + lr;
    float bias = bkv[gcol];
    int c = (gcol >= DIM) ? (gcol - DIM) : gcol;  // gcol % 384
    int h = c >> 5;
    int hd = c & 31;
    short* dst = (gcol < DIM) ? Kws : Vws;
#pragma unroll
    for (int m = 0; m < 4; ++m) {
#pragma unroll
      for (int r = 0; r < 4; ++r) {
        int grow = m0 + wm + m * 16 + rq + r;
        int bb = grow / NTOK;
        int tok = grow - bb * NTOK;
        dst[(((size_t)bb * NHEAD + h) * NTOK + tok) * HDIM + hd] =
            f2bf(acc[m][n][r] + bias);
      }
    }
  }
}

// ---------- kernel 2: fused attention per (b, h) — swapped-QK^T form --------
// R14-exact body (R15's register prefetch spilled to scratch -> reverted).
// bias+mask folded into MFMA C-in; no max-sub (log2-domain, bounded);
// deferred normalization; XOR bank swizzle on LDS.
__global__ __launch_bounds__(256, 3) void attn_kernel(
    const float* __restrict__ x_up, const short* __restrict__ mask_b4,
    const short* __restrict__ bias_b4, const short* __restrict__ Kws,
    const short* __restrict__ Vws, const float* __restrict__ pos,
    short* __restrict__ attn_out) {
  __shared__ short Ksm[NPAD][40];      // K[key][ch], col ^= (key&8)
  __shared__ short Vp[HDIM][NPAD + 8]; // V^T[ch][pi(key) ^ (ch&8)]
  const int bid = blockIdx.x;
  const int xcd = bid & 7;
  const int jj = bid >> 3;                 // 0..191
  const int win = xcd * 8 + jj / 24;       // 0..63, pinned to xcd
  const int rep = jj - (jj / 24) * 24;     // 0..23
  const int h = rep % NHEAD;
  const int b = win + ((rep >= NHEAD) ? 64 : 0);
  const int tid = threadIdx.x;
  const int wave = tid >> 6;
  const int lane = tid & 63;
  const int lr = lane & 15;
  const int lg = lane >> 4;
  const int koff = lg * 8;
  const int koff_s = koff ^ (lane & 8);
  const f32x4 zero4 = {0.f, 0.f, 0.f, 0.f};

  const short* Kb = Kws + ((size_t)b * NHEAD + h) * NTOK * HDIM;
  const short* Vb = Vws + ((size_t)b * NHEAD + h) * NTOK * HDIM;
  {
    const int c8 = (tid & 3) * 8;
    const int rb = tid >> 2;
    const bf16x8 z8 = {0, 0, 0, 0, 0, 0, 0, 0};
#pragma unroll
    for (int r0 = 0; r0 < 384; r0 += 64) {
      int row = r0 + rb;
      if (row < NPAD) {
        bf16x8 kv = z8;
        if (row < NTOK) kv = *(const bf16x8*)(Kb + row * HDIM + c8);
        *(bf16x8*)(&Ksm[row][c8 ^ (row & 8)]) = kv;
      }
    }
#pragma unroll
    for (int r0 = 0; r0 < 384; r0 += 64) {
      int row = r0 + rb;
      if (row < NPAD) {
        bf16x8 vv = z8;
        if (row < NTOK) vv = *(const bf16x8*)(Vb + row * HDIM + c8);
        // pi(row): k-slot = ((m&16)>>2) | ((m&12)<<1) | (m&3) within 32-block
        int p = (row & ~31) | ((row & 12) << 1) | ((row & 16) >> 2) | (row & 3);
#pragma unroll
        for (int i = 0; i < 8; ++i)
          Vp[c8 + i][p ^ ((c8 + i) & 8)] = vv[i];
      }
    }
  }
  __syncthreads();

  for (int qt = 0; qt < 6; ++qt) {
    const int q0 = qt * 64 + wave * 16;
    if (q0 >= NTOK) continue;
    const int qn = q0 + lr;
    const int qidx = (qn < NTOK) ? qn : (NTOK - 1);
    // Q B-frag scaled by SCALE*LOG2E (exp2 domain)
    bf16x8 qf;
    {
      const float* qp = x_up + ((size_t)b * NTOK + qidx) * DIM + h * HDIM + koff;
      f32x4 v0 = *(const f32x4*)qp;
      f32x4 v1 = *(const f32x4*)(qp + 4);
#pragma unroll
      for (int i = 0; i < 4; ++i) {
        qf[i] = f2bfrn(v0[i] * SCLG2);
        qf[i + 4] = f2bfrn(v1[i] * SCLG2);
      }
    }
    // bias+mask -> C-in (the MFMA adds them to QK^T on the matrix pipe)
    const short* bq = bias_b4 + (size_t)h * MG * GSTRIDE + (size_t)lg * GSTRIDE +
                      qidx * 4;
    const short* mq = mask_b4 + (size_t)win * MG * GSTRIDE + (size_t)lg * GSTRIDE +
                      qidx * 4;
    f32x4 s[22];
#pragma unroll
    for (int j = 0; j < 22; ++j) {
      bf16x4 bv = *(const bf16x4*)(bq + (size_t)j * 4 * GSTRIDE);
      bf16x4 mv = *(const bf16x4*)(mq + (size_t)j * 4 * GSTRIDE);
#pragma unroll
      for (int r = 0; r < 4; ++r) s[j][r] = bf2f(bv[r]) + bf2f(mv[r]);
    }
    // S^T tiles: s[j] = K_j * Q + (bias+mask)
    __builtin_amdgcn_s_setprio(1);
#pragma unroll
    for (int j = 0; j < 22; ++j) {
      bf16x8 kf = *(const bf16x8*)(&Ksm[j * 16 + lr][koff_s]);
      s[j] = MFMA16(kf, qf, s[j]);
    }
    __builtin_amdgcn_s_setprio(0);
    // p = exp2(s) directly (no max-sub). P packed UNNORMALIZED.
    f32x4 sum4 = zero4;
    i32x4 up4[11];
#pragma unroll
    for (int j = 0; j < 22; ++j) {
      f32x4 p;
#pragma unroll
      for (int r = 0; r < 4; ++r) p[r] = fexp2(s[j][r]);
      sum4 += p;
      up4[j >> 1][(j & 1) * 2 + 0] = pack2rn(p[0], p[1]);
      up4[j >> 1][(j & 1) * 2 + 1] = pack2rn(p[2], p[3]);
    }
    float sum = (sum4[0] + sum4[1]) + (sum4[2] + sum4[3]);
    sum += __shfl_xor(sum, 16);
    sum += __shfl_xor(sum, 32);
    const float inv = 1.0f / sum;

    // O^T = V^T_pi * P~ (unnormalized)
    f32x4 o0 = zero4;
    f32x4 o1 = zero4;
    __builtin_amdgcn_s_setprio(1);
#pragma unroll
    for (int kt = 0; kt < 11; ++kt) {
      bf16x8 pf = __builtin_bit_cast(bf16x8, up4[kt]);
      bf16x8 a0 = *(const bf16x8*)(&Vp[lr][kt * 32 + koff_s]);
      bf16x8 a1 = *(const bf16x8*)(&Vp[16 + lr][kt * 32 + koff_s]);
      o0 = MFMA16(a0, pf, o0);
      o1 = MFMA16(a1, pf, o1);
    }
    __builtin_amdgcn_s_setprio(0);
    // O is UNNORMALIZED -> the *inv below is REQUIRED, exactly once.
    if (qn < NTOK) {
      const float* pp = pos + ((size_t)b * NTOK + qn) * DIM + h * HDIM + 4 * lg;
      f32x4 p0 = *(const f32x4*)pp;
      f32x4 p1 = *(const f32x4*)(pp + 16);
      short* op = attn_out + ((size_t)b * NTOK + qn) * DIM + h * HDIM + 4 * lg;
      *(int*)(op + 0) = pack2rn(o0[0] * inv + p0[0], o0[1] * inv + p0[1]);
      *(int*)(op + 2) = pack2rn(o0[2] * inv + p0[2], o0[3] * inv + p0[3]);
      *(int*)(op + 16) = pack2rn(o1[0] * inv + p1[0], o1[1] * inv + p1[1]);
      *(int*)(op + 18) = pack2rn(o1[2] * inv + p1[2], o1[3] * inv + p1[3]);
    }
  }
}

// ---------- kernel 3: out = Xa @ wproj_bf^T + b_proj (Xa = attn+pos) --------
__global__ __launch_bounds__(256) void out_proj_kernel(
    const short* __restrict__ Xa, const short* __restrict__ Wbf,
    const float* __restrict__ bpr, float* __restrict__ out) {
  __shared__ short As[128][40];
  __shared__ short Bs[128][40];
  const int L = blockIdx.x;            // 0..1028
  const int xcd = L & 7;
  const int j8 = L >> 3;
  const int wg = ((xcd < 5) ? xcd * 129 : 645 + (xcd - 5) * 128) + j8;
  const int n0 = (wg % 3) * 128;
  const int m0 = (wg / 3) * 128;
  const int tid = threadIdx.x;
  const int lane = tid & 63;
  const int wave = tid >> 6;
  const int wm = (wave >> 1) * 64;
  const int wn = (wave & 1) * 64;
  const int lr = lane & 15;
  const int lk = (lane >> 4) * 8;
  const int arow = tid >> 2;
  const int acol8 = (tid & 3) * 8;
  const f32x4 zero4 = {0.f, 0.f, 0.f, 0.f};

  f32x4 acc[4][4];
#pragma unroll
  for (int m = 0; m < 4; ++m)
#pragma unroll
    for (int n = 0; n < 4; ++n) acc[m][n] = zero4;

  for (int kk = 0; kk < 12; ++kk) {
    __syncthreads();
    *(bf16x8*)(&As[arow][acol8]) =
        *(const bf16x8*)(Xa + (size_t)(m0 + arow) * DIM + kk * 32 + acol8);
    *(bf16x8*)(&As[arow + 64][acol8]) =
        *(const bf16x8*)(Xa + (size_t)(m0 + arow + 64) * DIM + kk * 32 + acol8);
    *(bf16x8*)(&Bs[arow][acol8]) =
        *(const bf16x8*)(Wbf + (size_t)(n0 + arow) * DIM + kk * 32 + acol8);
    *(bf16x8*)(&Bs[arow + 64][acol8]) =
        *(const bf16x8*)(Wbf + (size_t)(n0 + arow + 64) * DIM + kk * 32 + acol8);
    __syncthreads();
    bf16x8 af[4], bf[4];
#pragma unroll
    for (int m = 0; m < 4; ++m) af[m] = *(const bf16x8*)(&As[wm + m * 16 + lr][lk]);
#pragma unroll
    for (int n = 0; n < 4; ++n) bf[n] = *(const bf16x8*)(&Bs[wn + n * 16 + lr][lk]);
#pragma unroll
    for (int m = 0; m < 4; ++m)
#pragma unroll
      for (int n = 0; n < 4; ++n) acc[m][n] = MFMA16(af[m], bf[n], acc[m][n]);
  }

  const int rq = (lane >> 4) * 4;
#pragma unroll
  for (int n = 0; n < 4; ++n) {
    int gcol = n0 + wn + n * 16 + lr;
    float bias = bpr[gcol];
#pragma unroll
    for (int m = 0; m < 4; ++m) {
#pragma unroll
      for (int r = 0; r < 4; ++r) {
        int grow = m0 + wm + m * 16 + rq + r;
        out[(size_t)grow * DIM + gcol] = acc[m][n][r] + bias;
      }
    }
  }
}

extern "C" void kernel_launch(void* const* d_in, const int* in_sizes, int n_in,
                              void* d_out, int out_size, void* d_ws, size_t ws_size,
                              hipStream_t stream) {
  const float* skip = (const float*)d_in[0];
  const float* x_up = (const float*)d_in[1];
  const float* pos = (const float*)d_in[2];
  const float* mask = (const float*)d_in[3];
  const float* w_kv = (const float*)d_in[4];
  const float* b_kv = (const float*)d_in[5];
  const float* w_proj = (const float*)d_in[6];
  const float* b_proj = (const float*)d_in[7];
  const float* bias_table = (const float*)d_in[8];
  const int* rpi = (const int*)d_in[9];
  float* out = (float*)d_out;

  char* ws = (char*)d_ws;
  const size_t kv_bytes = (size_t)BATCH * NHEAD * NTOK * HDIM * 2;   // 33,718,272
  const size_t bias_bytes = (size_t)NHEAD * MG * NTOK * 4 * 2;       //  2,897,664
  const size_t mask_bytes = (size_t)NWIN * MG * NTOK * 4 * 2;        // 15,454,208
  const size_t wkv_bytes = (size_t)2 * DIM * DIM * 2;                //    589,824
  const size_t wpr_bytes = (size_t)DIM * DIM * 2;                    //    294,912
  short* Kws = (short*)ws;
  short* Vws = (short*)(ws + kv_bytes);
  short* bias_b4 = (short*)(ws + 2 * kv_bytes);
  short* mask_b4 = (short*)(ws + 2 * kv_bytes + bias_bytes);
  short* wkv_bf = (short*)(ws + 2 * kv_bytes + bias_bytes + mask_bytes);
  short* wproj_bf = (short*)(ws + 2 * kv_bytes + bias_bytes + mask_bytes + wkv_bytes);
  // skip_bf and attn_ws alias: prep->kv_proj finish before attn writes it
  short* skip_bf = (short*)(ws + 2 * kv_bytes + bias_bytes + mask_bytes +
                            wkv_bytes + wpr_bytes);
  short* attn_ws = skip_bf;

  prep_kernel<<<dim3(GB + GM + GS + GWK + GWP), dim3(256), 0, stream>>>(
      bias_table, rpi, bias_b4, mask, mask_b4, skip, skip_bf, w_kv, wkv_bf,
      w_proj, wproj_bf);
  kv_proj_kernel<<<dim3(2058), dim3(256), 0, stream>>>(skip_bf, wkv_bf, b_kv,
                                                       Kws, Vws);
  attn_kernel<<<dim3(BATCH * NHEAD), dim3(256), 0, stream>>>(
      x_up, mask_b4, bias_b4, Kws, Vws, pos, attn_ws);
  out_proj_kernel<<<dim3(1029), dim3(256), 0, stream>>>(attn_ws, wproj_bf,
                                                        b_proj, out);
}